// Round 10
// baseline (3720.213 us; speedup 1.0000x reference)
//
#include <hip/hip_runtime.h>
#include <hip/hip_bf16.h>
#include <math.h>

#define TD 2048   // hidden dim D
#define TE 8      // experts
#define TF 4096   // ffn dim F
#define TOPK 2

__device__ __forceinline__ float silu_f(float x) {
  return x / (1.0f + expf(-x));
}

// ---------------- init: zero the atomic counters ----------------
__global__ void init_kernel(int* counts) {
  if (threadIdx.x < TE) counts[threadIdx.x] = 0;
}

// ---------------- zero d_out (fallback path only; d_out is poisoned 0xAA) ----
__global__ void zero_out_kernel(float* __restrict__ out, int n4) {
  int i = blockIdx.x * 256 + threadIdx.x;
  if (i < n4) ((float4*)out)[i] = make_float4(0.f, 0.f, 0.f, 0.f);
}

// ---------------- router: logits -> softmax -> top2 -> renorm ----------------
__global__ __launch_bounds__(256) void router_kernel(
    const float* __restrict__ x, const float* __restrict__ rw,
    int* __restrict__ counts, int* __restrict__ tok_e,
    float* __restrict__ tok_wt, int T) {
  __shared__ float rwl[TE][TD];  // 64 KiB
  for (int i = threadIdx.x; i < TD * TE; i += 256) {
    int d = i >> 3, e = i & 7;
    rwl[e][d] = rw[i];
  }
  __syncthreads();

  const int wave = threadIdx.x >> 6;
  const int lane = threadIdx.x & 63;
  const int t0 = blockIdx.x * 32 + wave * 8;

  for (int ti = 0; ti < 8; ++ti) {
    int t = t0 + ti;
    if (t >= T) break;
    float acc[TE];
#pragma unroll
    for (int e = 0; e < TE; ++e) acc[e] = 0.f;
    const float* xr = x + (size_t)t * TD;
    for (int d = lane; d < TD; d += 64) {
      float xv = xr[d];
#pragma unroll
      for (int e = 0; e < TE; ++e) acc[e] = fmaf(xv, rwl[e][d], acc[e]);
    }
#pragma unroll
    for (int e = 0; e < TE; ++e) {
#pragma unroll
      for (int s = 32; s > 0; s >>= 1) acc[e] += __shfl_xor(acc[e], s, 64);
    }
    if (lane == 0) {
      float m = acc[0];
#pragma unroll
      for (int e = 1; e < TE; ++e) m = fmaxf(m, acc[e]);
      float p[TE];
#pragma unroll
      for (int e = 0; e < TE; ++e) p[e] = expf(acc[e] - m);
      int e0 = 0;
#pragma unroll
      for (int e = 1; e < TE; ++e) if (p[e] > p[e0]) e0 = e;
      int e1 = -1;
#pragma unroll
      for (int e = 0; e < TE; ++e) {
        if (e == e0) continue;
        if (e1 < 0 || p[e] > p[e1]) e1 = e;
      }
      float w0 = p[e0], w1 = p[e1];
      float inv = 1.f / (w0 + w1);
      tok_e[2 * t] = e0;
      tok_e[2 * t + 1] = e1;
      tok_wt[2 * t] = w0 * inv;
      tok_wt[2 * t + 1] = w1 * inv;
      atomicAdd(&counts[e0], 1);
      atomicAdd(&counts[e1], 1);
    }
  }
}

// ---------------- scan: exclusive prefix over 8 counts ----------------
__global__ void scan_kernel(const int* __restrict__ counts,
                            int* __restrict__ offsets, int* __restrict__ cursor) {
  if (threadIdx.x == 0) {
    int o = 0;
    for (int e = 0; e < TE; ++e) {
      offsets[e] = o;
      cursor[e] = o;
      o += counts[e];
    }
    offsets[TE] = o;
  }
}

// ---------------- build compact per-expert token lists ----------------
__global__ void build_kernel(const int* __restrict__ tok_e,
                             const float* __restrict__ tok_wt,
                             int* __restrict__ cursor, int* __restrict__ tok_id,
                             float* __restrict__ slot_w, int* __restrict__ slot_of,
                             int T) {
  int t = blockIdx.x * 256 + threadIdx.x;
  if (t >= T) return;
  for (int k = 0; k < TOPK; ++k) {
    int e = tok_e[2 * t + k];
    int pos = atomicAdd(&cursor[e], 1);
    tok_id[pos] = t;
    slot_w[pos] = tok_wt[2 * t + k];
    slot_of[2 * t + k] = pos;
  }
}

// ---------------- GEMM1: H[slot][f] = silu(x@w1[e]) * (x@v1[e]) ----------------
// BM=128, BN=128, BK=16, 256 threads, 8x8 microtile, dual-B (w1 & v1 share A).
__global__ __launch_bounds__(256) void gemm1_kernel(
    const float* __restrict__ x, const float* __restrict__ w1,
    const float* __restrict__ v1, const int* __restrict__ offsets,
    const int* __restrict__ tok_id, float* __restrict__ H) {
  const int e = blockIdx.z;
  const int off = offsets[e];
  const int ne = offsets[e + 1] - off;
  const int m0 = blockIdx.y * 128;
  if (m0 >= ne) return;
  const int n0 = blockIdx.x * 128;

  __shared__ float As[16][132];  // transposed: As[k][m]
  __shared__ float Bs[16][132];
  __shared__ float Cs[16][132];
  __shared__ int toks[128];

  const int tid = threadIdx.x;
  if (tid < 128) {
    int gm = m0 + tid;
    toks[tid] = tok_id[off + (gm < ne ? gm : 0)];
  }
  __syncthreads();

  const int am = tid >> 1;          // 0..127 (row within tile)
  const int ak = (tid & 1) << 3;    // 0 or 8 (k offset)
  const int bk = tid >> 4;          // 0..15
  const int bn = (tid & 15) << 2;   // 0..60
  const int tx = tid & 15;
  const int ty = tid >> 4;

  float acc1[8][8], acc2[8][8];
#pragma unroll
  for (int i = 0; i < 8; ++i)
#pragma unroll
    for (int j = 0; j < 8; ++j) { acc1[i][j] = 0.f; acc2[i][j] = 0.f; }

  const float* arow = x + (size_t)toks[am] * TD;
  const size_t bbase = (size_t)e * TD * TF + n0;

  // prefetch k-tile 0 into registers
  float4 a0 = *(const float4*)(arow + ak);
  float4 a1 = *(const float4*)(arow + ak + 4);
  const float* bp = w1 + bbase + (size_t)bk * TF;
  const float* cp = v1 + bbase + (size_t)bk * TF;
  float4 b0 = *(const float4*)(bp + bn);
  float4 b1 = *(const float4*)(bp + bn + 64);
  float4 c0 = *(const float4*)(cp + bn);
  float4 c1 = *(const float4*)(cp + bn + 64);

  for (int k0 = 0; k0 < TD; k0 += 16) {
    __syncthreads();  // previous compute done; LDS free
    As[ak + 0][am] = a0.x; As[ak + 1][am] = a0.y;
    As[ak + 2][am] = a0.z; As[ak + 3][am] = a0.w;
    As[ak + 4][am] = a1.x; As[ak + 5][am] = a1.y;
    As[ak + 6][am] = a1.z; As[ak + 7][am] = a1.w;
    *(float4*)&Bs[bk][bn] = b0;
    *(float4*)&Bs[bk][bn + 64] = b1;
    *(float4*)&Cs[bk][bn] = c0;
    *(float4*)&Cs[bk][bn + 64] = c1;
    __syncthreads();  // LDS ready

    int kn = k0 + 16;
    if (kn < TD) {  // issue next tile's loads; overlap with FMA block below
      a0 = *(const float4*)(arow + kn + ak);
      a1 = *(const float4*)(arow + kn + ak + 4);
      const float* bpn = w1 + bbase + (size_t)(kn + bk) * TF;
      const float* cpn = v1 + bbase + (size_t)(kn + bk) * TF;
      b0 = *(const float4*)(bpn + bn);
      b1 = *(const float4*)(bpn + bn + 64);
      c0 = *(const float4*)(cpn + bn);
      c1 = *(const float4*)(cpn + bn + 64);
    }

#pragma unroll
    for (int k = 0; k < 16; ++k) {
      float a[8], b[8], c[8];
      *(float4*)&a[0] = *(const float4*)&As[k][ty * 4];
      *(float4*)&a[4] = *(const float4*)&As[k][ty * 4 + 64];
      *(float4*)&b[0] = *(const float4*)&Bs[k][tx * 4];
      *(float4*)&b[4] = *(const float4*)&Bs[k][tx * 4 + 64];
      *(float4*)&c[0] = *(const float4*)&Cs[k][tx * 4];
      *(float4*)&c[4] = *(const float4*)&Cs[k][tx * 4 + 64];
#pragma unroll
      for (int i = 0; i < 8; ++i)
#pragma unroll
        for (int j = 0; j < 8; ++j) {
          acc1[i][j] = fmaf(a[i], b[j], acc1[i][j]);
          acc2[i][j] = fmaf(a[i], c[j], acc2[i][j]);
        }
    }
  }

#pragma unroll
  for (int i = 0; i < 8; ++i) {
    int m = ty * 4 + ((i >> 2) << 6) + (i & 3);
    if (m0 + m < ne) {
      float* orow = H + (size_t)(off + m0 + m) * TF + n0;
      float4 o0, o1;
      o0.x = silu_f(acc1[i][0]) * acc2[i][0];
      o0.y = silu_f(acc1[i][1]) * acc2[i][1];
      o0.z = silu_f(acc1[i][2]) * acc2[i][2];
      o0.w = silu_f(acc1[i][3]) * acc2[i][3];
      o1.x = silu_f(acc1[i][4]) * acc2[i][4];
      o1.y = silu_f(acc1[i][5]) * acc2[i][5];
      o1.z = silu_f(acc1[i][6]) * acc2[i][6];
      o1.w = silu_f(acc1[i][7]) * acc2[i][7];
      *(float4*)(orow + tx * 4) = o0;
      *(float4*)(orow + tx * 4 + 64) = o1;
    }
  }
}

// ---------------- GEMM2 core (shared by both store variants) ----------------
// ATOMIC=0: out_c[slot][d] = slot_w * (H[slot] @ w2[e])   (primary)
// ATOMIC=1: atomicAdd(&out[tok_id[slot]][d], ...)          (low-ws fallback;
//           exactly 2 commutative fp32 adds per element -> bit-deterministic)
template <int ATOMIC>
__global__ __launch_bounds__(256) void gemm2_kernel_t(
    const float* __restrict__ H, const float* __restrict__ w2,
    const int* __restrict__ offsets, const float* __restrict__ slot_w,
    const int* __restrict__ tok_id, float* __restrict__ outp) {
  const int e = blockIdx.z;
  const int off = offsets[e];
  const int ne = offsets[e + 1] - off;
  const int m0 = blockIdx.y * 128;
  if (m0 >= ne) return;
  const int n0 = blockIdx.x * 128;

  __shared__ float As[16][132];
  __shared__ float Bs[16][132];

  const int tid = threadIdx.x;
  const int am = tid >> 1;
  const int ak = (tid & 1) << 3;
  const int bk = tid >> 4;
  const int bn = (tid & 15) << 2;
  const int tx = tid & 15;
  const int ty = tid >> 4;

  float acc[8][8];
#pragma unroll
  for (int i = 0; i < 8; ++i)
#pragma unroll
    for (int j = 0; j < 8; ++j) acc[i][j] = 0.f;

  int amr = m0 + am;
  if (amr >= ne) amr = m0;  // duplicate a valid row; masked at store
  const float* arow = H + (size_t)(off + amr) * TF;
  const size_t bbase = (size_t)e * TF * TD + n0;

  // prefetch k-tile 0
  float4 a0 = *(const float4*)(arow + ak);
  float4 a1 = *(const float4*)(arow + ak + 4);
  const float* bp = w2 + bbase + (size_t)bk * TD;
  float4 b0 = *(const float4*)(bp + bn);
  float4 b1 = *(const float4*)(bp + bn + 64);

  for (int k0 = 0; k0 < TF; k0 += 16) {
    __syncthreads();
    As[ak + 0][am] = a0.x; As[ak + 1][am] = a0.y;
    As[ak + 2][am] = a0.z; As[ak + 3][am] = a0.w;
    As[ak + 4][am] = a1.x; As[ak + 5][am] = a1.y;
    As[ak + 6][am] = a1.z; As[ak + 7][am] = a1.w;
    *(float4*)&Bs[bk][bn] = b0;
    *(float4*)&Bs[bk][bn + 64] = b1;
    __syncthreads();

    int kn = k0 + 16;
    if (kn < TF) {
      a0 = *(const float4*)(arow + kn + ak);
      a1 = *(const float4*)(arow + kn + ak + 4);
      const float* bpn = w2 + bbase + (size_t)(kn + bk) * TD;
      b0 = *(const float4*)(bpn + bn);
      b1 = *(const float4*)(bpn + bn + 64);
    }

#pragma unroll
    for (int k = 0; k < 16; ++k) {
      float a[8], b[8];
      *(float4*)&a[0] = *(const float4*)&As[k][ty * 4];
      *(float4*)&a[4] = *(const float4*)&As[k][ty * 4 + 64];
      *(float4*)&b[0] = *(const float4*)&Bs[k][tx * 4];
      *(float4*)&b[4] = *(const float4*)&Bs[k][tx * 4 + 64];
#pragma unroll
      for (int i = 0; i < 8; ++i)
#pragma unroll
        for (int j = 0; j < 8; ++j) acc[i][j] = fmaf(a[i], b[j], acc[i][j]);
    }
  }

#pragma unroll
  for (int i = 0; i < 8; ++i) {
    int m = ty * 4 + ((i >> 2) << 6) + (i & 3);
    if (m0 + m < ne) {
      int slot = off + m0 + m;
      float w = slot_w[slot];
      if (ATOMIC) {
        float* orow = outp + (size_t)tok_id[slot] * TD + n0;
#pragma unroll
        for (int j = 0; j < 4; ++j) {
          atomicAdd(orow + tx * 4 + j, acc[i][j] * w);
          atomicAdd(orow + tx * 4 + 64 + j, acc[i][j + 4] * w);
        }
      } else {
        float* orow = outp + (size_t)slot * TD + n0;
        float4 o0, o1;
        o0.x = acc[i][0] * w; o0.y = acc[i][1] * w;
        o0.z = acc[i][2] * w; o0.w = acc[i][3] * w;
        o1.x = acc[i][4] * w; o1.y = acc[i][5] * w;
        o1.z = acc[i][6] * w; o1.w = acc[i][7] * w;
        *(float4*)(orow + tx * 4) = o0;
        *(float4*)(orow + tx * 4 + 64) = o1;
      }
    }
  }
}

// ---------------- combine: out[t] = out_c[slot0] + out_c[slot1] ----------------
__global__ __launch_bounds__(256) void combine_kernel(
    const float* __restrict__ out_c, const int* __restrict__ slot_of,
    float* __restrict__ out) {
  int t = blockIdx.x;
  int s0 = slot_of[2 * t];
  int s1 = slot_of[2 * t + 1];
  const float4* r0 = (const float4*)(out_c + (size_t)s0 * TD);
  const float4* r1 = (const float4*)(out_c + (size_t)s1 * TD);
  float4* o = (float4*)(out + (size_t)t * TD);
  for (int i = threadIdx.x; i < TD / 4; i += 256) {
    float4 a = r0[i], b = r1[i];
    o[i] = make_float4(a.x + b.x, a.y + b.y, a.z + b.z, a.w + b.w);
  }
}

extern "C" void kernel_launch(void* const* d_in, const int* in_sizes, int n_in,
                              void* d_out, int out_size, void* d_ws, size_t ws_size,
                              hipStream_t stream) {
  const float* x  = (const float*)d_in[0];
  const float* rw = (const float*)d_in[1];
  const float* w1 = (const float*)d_in[2];
  const float* v1 = (const float*)d_in[3];
  const float* w2 = (const float*)d_in[4];
  float* out = (float*)d_out;

  const int T = in_sizes[0] / TD;  // 2048 tokens
  const int A = TOPK * T;          // 4096 assignments

  char* ws = (char*)d_ws;
  int*   counts  = (int*)ws;
  int*   cursor  = (int*)(ws + 64);
  int*   offsets = (int*)(ws + 128);
  int*   tok_e   = (int*)(ws + 256);
  float* tok_wt  = (float*)(ws + 256 + 4 * (size_t)A);
  int*   slot_of = (int*)(ws + 256 + 8 * (size_t)A);
  int*   tok_id  = (int*)(ws + 256 + 12 * (size_t)A);
  float* slot_w  = (float*)(ws + 256 + 16 * (size_t)A);
  size_t hoff = (256 + 20 * (size_t)A + 255) & ~(size_t)255;
  float* H     = (float*)(ws + hoff);
  float* out_c = (float*)(ws + hoff + (size_t)A * TF * 4);

  const size_t need_full = hoff + (size_t)A * TF * 4 + (size_t)A * TD * 4;
  const bool full = ws_size >= need_full;  // deterministic per-process: capture-safe

  init_kernel<<<1, 64, 0, stream>>>(counts);
  router_kernel<<<T / 32, 256, 0, stream>>>(x, rw, counts, tok_e, tok_wt, T);
  scan_kernel<<<1, 64, 0, stream>>>(counts, offsets, cursor);
  build_kernel<<<(T + 255) / 256, 256, 0, stream>>>(tok_e, tok_wt, cursor,
                                                    tok_id, slot_w, slot_of, T);
  dim3 g1(TF / 128, T / 128, TE);
  gemm1_kernel<<<g1, 256, 0, stream>>>(x, w1, v1, offsets, tok_id, H);
  dim3 g2(TD / 128, T / 128, TE);
  if (full) {
    gemm2_kernel_t<0><<<g2, 256, 0, stream>>>(H, w2, offsets, slot_w, tok_id, out_c);
    combine_kernel<<<T, 256, 0, stream>>>(out_c, slot_of, out);
  } else {
    // low-workspace fallback: zero d_out, then accumulate expert outputs directly
    zero_out_kernel<<<(T * TD / 4 + 255) / 256, 256, 0, stream>>>(out, T * TD / 4);
    gemm2_kernel_t<1><<<g2, 256, 0, stream>>>(H, w2, offsets, slot_w, tok_id, out);
  }
}